// Round 16
// baseline (103.574 us; speedup 1.0000x reference)
//
#include <hip/hip_runtime.h>

#define N_NODES 100000
#define N_EDGES 1250000
#define D 64
#define BSH 6                  // 64 nodes per bucket
#define BNODES 64
#define NB 1563                // ceil(100000/64)
#define WSW 68                 // LDS row stride (floats) for fallback GEMM
#define MM_BLOCKS ((N_NODES + 127) / 128)     // 782
#define BIN_BLOCKS2 1024
#define BIN_CHUNK2 1224        // 8-aligned; 1024*1224 >= 1.25M
#define BIN_BLOCKS 128
#define BIN_CHUNK ((N_EDGES + BIN_BLOCKS - 1) / BIN_BLOCKS)

typedef unsigned int u32;
typedef short bf16x8 __attribute__((ext_vector_type(8)));   // 8 bf16 = 4 VGPRs
typedef float f32x4 __attribute__((ext_vector_type(4)));

__device__ __forceinline__ u32 pack_bf16(float lo, float hi) {
    u32 a = __float_as_uint(lo);
    u32 b = __float_as_uint(hi);
    a = (a + 0x7fffu + ((a >> 16) & 1u)) >> 16;   // RNE
    b = (b + 0x7fffu + ((b >> 16) & 1u)) >> 16;
    return a | (b << 16);
}

// ---------------------------------------------------------------------------
// Fused binning || MFMA GEMM, one dispatch.
// Blocks 0..1023: LDS-privatized histogram of a 1224-edge chunk; ONE global
//   atomicAdd per (block,bucket) to reserve a range (staggered sweep to avoid
//   same-address convoys); scatter into reserved slots. 4 blocks/CU -> 16
//   waves/CU hides latency (round-6's 55us was 0.5 block/CU, not atomics).
// Blocks 1024..1805: MFMA GEMM [Y|Z] = bf16(x) @ [Wn^T|Ws^T]; B-fragments
//   built directly from L2-hot wn/wsf (2 float4 + pack per frag) - no wprep.
// ---------------------------------------------------------------------------
__global__ void __launch_bounds__(256) k_binmm(const int* __restrict__ ei,
                                               u32* __restrict__ bcnt,
                                               u32* __restrict__ binned,
                                               int cap,
                                               const float* __restrict__ x,
                                               const float* __restrict__ wn,
                                               const float* __restrict__ wsf,
                                               const float* __restrict__ bias,
                                               u32* __restrict__ y16,
                                               float* __restrict__ zout) {
    __shared__ u32 hist[NB];
    __shared__ u32 rbase[NB];
    int tid = threadIdx.x;
    if (blockIdx.x < BIN_BLOCKS2) {
        int g = blockIdx.x;
        int e0 = g * BIN_CHUNK2;
        int e1 = min(e0 + BIN_CHUNK2, N_EDGES);
        int ne = e1 - e0;                       // multiple of 4 (or <=0)
        for (int i = tid; i < NB; i += 256) hist[i] = 0;
        __syncthreads();
        if (ne > 0) {
            const int4* dp = (const int4*)(ei + N_EDGES + e0);
            int nv = ne >> 2;
            for (int i = tid; i < nv; i += 256) {
                int4 d4 = dp[i];
                atomicAdd(&hist[d4.x >> BSH], 1u);
                atomicAdd(&hist[d4.y >> BSH], 1u);
                atomicAdd(&hist[d4.z >> BSH], 1u);
                atomicAdd(&hist[d4.w >> BSH], 1u);
            }
        }
        __syncthreads();
        int rot = (g * 97) % NB;                // stagger reservation sweep
        for (int i = tid; i < NB; i += 256) {
            int ii = i + rot;
            if (ii >= NB) ii -= NB;
            u32 h = hist[ii];
            rbase[ii] = h ? atomicAdd(&bcnt[ii], h) : 0u;
            hist[ii] = 0;                       // becomes local cursor
        }
        __syncthreads();
        if (ne > 0) {
            const int4* sp = (const int4*)(ei + e0);
            const int4* dp = (const int4*)(ei + N_EDGES + e0);
            int nv = ne >> 2;
            for (int i = tid; i < nv; i += 256) {
                int4 s4 = sp[i];
                int4 d4 = dp[i];
                int ss[4] = {s4.x, s4.y, s4.z, s4.w};
                int dd[4] = {d4.x, d4.y, d4.z, d4.w};
#pragma unroll
                for (int u = 0; u < 4; ++u) {
                    int b = dd[u] >> BSH;
                    u32 loc = atomicAdd(&hist[b], 1u);
                    u32 slot = rbase[b] + loc;
                    if (slot < (u32)cap)
                        binned[(size_t)b * cap + slot] =
                            ((u32)ss[u] << BSH) | (u32)(dd[u] & (BNODES - 1));
                }
            }
        }
        return;
    }

    // ---- MFMA GEMM part ----
    int w = tid >> 6, l = tid & 63;
    int lg = l >> 4, c = l & 15;
    int nodebase = (blockIdx.x - BIN_BLOCKS2) * 128 + w * 32;

    union FU { uint4 u; bf16x8 v; };

    bf16x8 af[2][2];
#pragma unroll
    for (int m = 0; m < 2; ++m) {
        int node = nodebase + m * 16 + c;
        if (node >= N_NODES) node = N_NODES - 1;
        const float4* xr = (const float4*)(x + (size_t)node * D);
#pragma unroll
        for (int h = 0; h < 2; ++h) {
            float4 p0 = xr[h * 8 + lg * 2];
            float4 p1 = xr[h * 8 + lg * 2 + 1];
            FU au;
            au.u.x = pack_bf16(p0.x, p0.y);
            au.u.y = pack_bf16(p0.z, p0.w);
            au.u.z = pack_bf16(p1.x, p1.y);
            au.u.w = pack_bf16(p1.z, p1.w);
            af[m][h] = au.v;
        }
    }

    f32x4 acc[2][8];
#pragma unroll
    for (int m = 0; m < 2; ++m) {
#pragma unroll
        for (int t = 0; t < 4; ++t) acc[m][t] = (f32x4){0.f, 0.f, 0.f, 0.f};
#pragma unroll
        for (int t = 4; t < 8; ++t) {
            float bb = bias[(t - 4) * 16 + c];
            acc[m][t] = (f32x4){bb, bb, bb, bb};
        }
    }

    // B fragments direct from weights: lane l, tile t -> row n = t*16 + c of
    // [Wn^T|Ws^T]; half h -> 8 consecutive floats at k0 = h*32 + lg*8.
#pragma unroll
    for (int tc = 0; tc < 2; ++tc) {
        bf16x8 bf[4][2];
#pragma unroll
        for (int tt = 0; tt < 4; ++tt) {
            int n = (tc * 4 + tt) * 16 + c;
            const float* wrow = (n < 64) ? &wn[(size_t)n * 64]
                                         : &wsf[(size_t)(n - 64) * 64];
#pragma unroll
            for (int h = 0; h < 2; ++h) {
                int k0 = h * 32 + lg * 8;
                float4 q0 = *(const float4*)&wrow[k0];
                float4 q1 = *(const float4*)&wrow[k0 + 4];
                FU bu;
                bu.u.x = pack_bf16(q0.x, q0.y);
                bu.u.y = pack_bf16(q0.z, q0.w);
                bu.u.z = pack_bf16(q1.x, q1.y);
                bu.u.w = pack_bf16(q1.z, q1.w);
                bf[tt][h] = bu.v;
            }
        }
#pragma unroll
        for (int m = 0; m < 2; ++m)
#pragma unroll
            for (int tt = 0; tt < 4; ++tt) {
                int t = tc * 4 + tt;
                acc[m][t] = __builtin_amdgcn_mfma_f32_16x16x32_bf16(
                    af[m][0], bf[tt][0], acc[m][t], 0, 0, 0);
                acc[m][t] = __builtin_amdgcn_mfma_f32_16x16x32_bf16(
                    af[m][1], bf[tt][1], acc[m][t], 0, 0, 0);
            }
    }

#pragma unroll
    for (int m = 0; m < 2; ++m) {
        int rowbase = nodebase + m * 16 + lg * 4;
#pragma unroll
        for (int r = 0; r < 4; ++r) {
            int node = rowbase + r;
            bool ok = node < N_NODES;
#pragma unroll
            for (int t = 4; t < 8; ++t) {
                if (ok) zout[(size_t)node * D + (t - 4) * 16 + c] = acc[m][t][r];
            }
#pragma unroll
            for (int t = 0; t < 4; ++t) {
                float v = acc[m][t][r];
                float o = __shfl_xor(v, 1);
                if (ok && !(c & 1))
                    y16[(size_t)node * 32 + t * 8 + (c >> 1)] = pack_bf16(v, o);
            }
        }
    }
}

// ---------------------------------------------------------------------------
// Fused sort + gather: one block = one bucket. Counting-sort the bucket's
// packed edges in LDS (u32 atomics only), then 4 waves gather 16 nodes each:
// 8 predicated uint2 Y-loads in flight, register accumulation,
// out[n] = Z[n] + mean.
// ---------------------------------------------------------------------------
__global__ void __launch_bounds__(256) k_sortgather(const u32* __restrict__ y16,
                                                    const u32* __restrict__ binned,
                                                    const u32* __restrict__ bcnt,
                                                    int cap,
                                                    float* __restrict__ io) {
    __shared__ u32 eh[1024];
    __shared__ u32 srt[1024];
    __shared__ u32 hist[BNODES];
    __shared__ u32 nbase[BNODES];
    __shared__ u32 cur[BNODES];
    int tid = threadIdx.x;
    int b = blockIdx.x;
    int cnt = min((int)bcnt[b], cap);
    const u32* seg = binned + (size_t)b * cap;

    if (tid < BNODES) hist[tid] = 0;
    __syncthreads();
    const uint4* segv = (const uint4*)seg;
    int nv = cnt >> 2;
    for (int i = tid; i < nv; i += 256) {
        uint4 w4 = segv[i];
        *(uint4*)&eh[4 * i] = w4;
        atomicAdd(&hist[w4.x & (BNODES - 1)], 1u);
        atomicAdd(&hist[w4.y & (BNODES - 1)], 1u);
        atomicAdd(&hist[w4.z & (BNODES - 1)], 1u);
        atomicAdd(&hist[w4.w & (BNODES - 1)], 1u);
    }
    for (int i = (cnt & ~3) + tid; i < cnt; i += 256) {
        u32 w = seg[i];
        eh[i] = w;
        atomicAdd(&hist[w & (BNODES - 1)], 1u);
    }
    __syncthreads();
    if (tid < BNODES) {
        u32 v = hist[tid];
        u32 s = v;
#pragma unroll
        for (int off = 1; off < 64; off <<= 1) {
            u32 n = __shfl_up(s, off, 64);
            if (tid >= off) s += n;
        }
        u32 excl = s - v;
        nbase[tid] = excl;
        cur[tid] = excl;
    }
    __syncthreads();
    for (int i = tid; i < cnt; i += 256) {
        u32 w = eh[i];
        u32 p = atomicAdd(&cur[w & (BNODES - 1)], 1u);
        srt[p] = w >> BSH;
    }
    __syncthreads();

    int wv = tid >> 6, lane = tid & 63;
    int sub = lane >> 4;
    int pr = lane & 15;
    const uint2* yv = (const uint2*)y16;
    int nodebase = b << BSH;

    for (int i = 0; i < 16; ++i) {
        int dl = wv * 16 + i;
        int node = nodebase + dl;
        u32 o0 = nbase[dl];
        u32 dg = hist[dl];
        float a0 = 0.f, a1 = 0.f, a2 = 0.f, a3 = 0.f;
        for (u32 r = 0; r < dg; r += 32) {
            uint2 w[8];
#pragma unroll
            for (int t = 0; t < 8; ++t) {
                u32 e = r + 4 * t + sub;
                w[t] = make_uint2(0u, 0u);
                if (e < dg) w[t] = yv[(size_t)srt[o0 + e] * 16 + pr];  // predicated
            }
#pragma unroll
            for (int t = 0; t < 8; ++t) {
                if (r + 4u * (u32)t < dg) {                            // wave-uniform skip
                    a0 += __uint_as_float(w[t].x << 16);
                    a1 += __uint_as_float(w[t].x & 0xffff0000u);
                    a2 += __uint_as_float(w[t].y << 16);
                    a3 += __uint_as_float(w[t].y & 0xffff0000u);
                }
            }
        }
        a0 += __shfl_xor(a0, 16); a1 += __shfl_xor(a1, 16);
        a2 += __shfl_xor(a2, 16); a3 += __shfl_xor(a3, 16);
        a0 += __shfl_xor(a0, 32); a1 += __shfl_xor(a1, 32);
        a2 += __shfl_xor(a2, 32); a3 += __shfl_xor(a3, 32);
        if (sub == 0 && node < N_NODES) {
            float inv = 1.0f / (float)max(dg, 1u);
            float4 z = *(const float4*)&io[(size_t)node * D + 4 * pr];
            *(float4*)&io[(size_t)node * D + 4 * pr] =
                make_float4(z.x + a0 * inv, z.y + a1 * inv, z.z + a2 * inv, z.w + a3 * inv);
        }
    }
}

// ======================= fallback path (small workspace) ====================
__global__ void __launch_bounds__(256) k_bin2(const int* __restrict__ ei,
                                              u32* __restrict__ bcnt,
                                              u32* __restrict__ binned,
                                              int cap) {
    __shared__ u32 hist[NB];
    __shared__ u32 rbase[NB];
    int tid = threadIdx.x;
    int e0 = blockIdx.x * BIN_CHUNK;
    int e1 = min(e0 + BIN_CHUNK, N_EDGES);
    const int* dstp = ei + N_EDGES;
    for (int i = tid; i < NB; i += 256) hist[i] = 0;
    __syncthreads();
    for (int e = e0 + tid; e < e1; e += 256)
        atomicAdd(&hist[dstp[e] >> BSH], 1u);
    __syncthreads();
    for (int i = tid; i < NB; i += 256) {
        u32 h = hist[i];
        rbase[i] = h ? atomicAdd(&bcnt[i], h) : 0u;
        hist[i] = 0;
    }
    __syncthreads();
    for (int e = e0 + tid; e < e1; e += 256) {
        int d = dstp[e];
        int s = ei[e];
        int b = d >> BSH;
        u32 loc = atomicAdd(&hist[b], 1u);
        u32 slot = rbase[b] + loc;
        if (slot < (u32)cap)
            binned[(size_t)b * cap + slot] = ((u32)s << BSH) | (u32)(d & (BNODES - 1));
    }
}

__global__ void __launch_bounds__(256) k_sort_fb(u32* __restrict__ binned,
                                                 const u32* __restrict__ bcnt,
                                                 int cap,
                                                 u32* __restrict__ offs,
                                                 u32* __restrict__ deg) {
    __shared__ u32 eh[1024];
    __shared__ u32 hist[BNODES];
    __shared__ u32 cur[BNODES];
    int tid = threadIdx.x;
    int b = blockIdx.x;
    int cnt = min((int)bcnt[b], cap);
    u32* seg = binned + (size_t)b * cap;
    if (tid < BNODES) hist[tid] = 0;
    __syncthreads();
    for (int i = tid; i < cnt; i += 256) {
        u32 w = seg[i];
        eh[i] = w;
        atomicAdd(&hist[w & (BNODES - 1)], 1u);
    }
    __syncthreads();
    if (tid < BNODES) {
        u32 v = hist[tid];
        u32 s = v;
#pragma unroll
        for (int off = 1; off < 64; off <<= 1) {
            u32 n = __shfl_up(s, off, 64);
            if (tid >= off) s += n;
        }
        u32 excl = s - v;
        cur[tid] = excl;
        int node = (b << BSH) + tid;
        if (node < N_NODES) {
            offs[node] = (u32)((size_t)b * cap + excl);
            deg[node] = v;
        }
    }
    __syncthreads();
    for (int i = tid; i < cnt; i += 256) {
        u32 w = eh[i];
        u32 p = atomicAdd(&cur[w & (BNODES - 1)], 1u);
        seg[p] = w >> BSH;
    }
}

__global__ void __launch_bounds__(256) k_gather32(const float* __restrict__ x,
                                                  const u32* __restrict__ binned,
                                                  const u32* __restrict__ offs,
                                                  const u32* __restrict__ deg,
                                                  float* __restrict__ agg) {
    int tid = blockIdx.x * 256 + threadIdx.x;
    int node = tid >> 6;
    int d = tid & 63;
    if (node >= N_NODES) return;
    u32 o0 = offs[node], dg = deg[node];
    u32 o1 = o0 + dg;
    float s = 0.f;
    u32 j = o0;
    for (; j + 8 <= o1; j += 8) {
        u32 e[8];
        float v[8];
#pragma unroll
        for (int t = 0; t < 8; ++t) e[t] = binned[j + t];
#pragma unroll
        for (int t = 0; t < 8; ++t) v[t] = x[(size_t)e[t] * D + d];
#pragma unroll
        for (int t = 0; t < 8; ++t) s += v[t];
    }
    for (; j < o1; ++j) s += x[(size_t)binned[j] * D + d];
    agg[(size_t)node * D + d] = s / (float)max(dg, 1u);
}

__global__ void __launch_bounds__(256) k_gemm_fb(const float* __restrict__ x,
                                                 const float* __restrict__ wn,
                                                 const float* __restrict__ wsf,
                                                 const float* __restrict__ bias,
                                                 float* __restrict__ io) {
    __shared__ float At[BNODES * WSW];
    __shared__ float Wt[128 * WSW];
    int tid = threadIdx.x;
    int base = blockIdx.x * 64;
    const float4* iop = (const float4*)io;
    const float4* xp  = (const float4*)x;
    for (int i = tid; i < 4096; i += 256) {
        int d = i >> 6, k = i & 63;
        Wt[k * WSW + d] = wn[i];
        Wt[(64 + k) * WSW + d] = wsf[i];
    }
    for (int i = tid; i < 1024; i += 256) {
        int r = i >> 4, q = i & 15;
        int node = base + r;
        float4 v = make_float4(0.f, 0.f, 0.f, 0.f);
        if (node < N_NODES) v = iop[(size_t)node * 16 + q];
        *(float4*)&At[r * WSW + q * 4] = v;
    }
    __syncthreads();
    int tn = tid >> 4, td = tid & 15;
    int n0 = tn * 4, d0 = td * 4;
    float4 b4 = *(const float4*)&bias[d0];
    float acc[4][4];
#pragma unroll
    for (int i = 0; i < 4; ++i) {
        acc[i][0] = b4.x; acc[i][1] = b4.y; acc[i][2] = b4.z; acc[i][3] = b4.w;
    }
#pragma unroll 8
    for (int kc = 0; kc < 16; ++kc) {
        float4 a[4], w[4];
#pragma unroll
        for (int i = 0; i < 4; ++i) a[i] = *(const float4*)&At[(n0 + i) * WSW + kc * 4];
#pragma unroll
        for (int t = 0; t < 4; ++t) w[t] = *(const float4*)&Wt[(kc * 4 + t) * WSW + d0];
#pragma unroll
        for (int i = 0; i < 4; ++i) {
            const float av[4] = {a[i].x, a[i].y, a[i].z, a[i].w};
#pragma unroll
            for (int t = 0; t < 4; ++t) {
                acc[i][0] += av[t] * w[t].x; acc[i][1] += av[t] * w[t].y;
                acc[i][2] += av[t] * w[t].z; acc[i][3] += av[t] * w[t].w;
            }
        }
    }
    __syncthreads();
    for (int i = tid; i < 1024; i += 256) {
        int r = i >> 4, q = i & 15;
        int node = base + r;
        float4 v = make_float4(0.f, 0.f, 0.f, 0.f);
        if (node < N_NODES) v = xp[(size_t)node * 16 + q];
        *(float4*)&At[r * WSW + q * 4] = v;
    }
    __syncthreads();
#pragma unroll 8
    for (int kc = 0; kc < 16; ++kc) {
        float4 a[4], w[4];
#pragma unroll
        for (int i = 0; i < 4; ++i) a[i] = *(const float4*)&At[(n0 + i) * WSW + kc * 4];
#pragma unroll
        for (int t = 0; t < 4; ++t) w[t] = *(const float4*)&Wt[(64 + kc * 4 + t) * WSW + d0];
#pragma unroll
        for (int i = 0; i < 4; ++i) {
            const float av[4] = {a[i].x, a[i].y, a[i].z, a[i].w};
#pragma unroll
            for (int t = 0; t < 4; ++t) {
                acc[i][0] += av[t] * w[t].x; acc[i][1] += av[t] * w[t].y;
                acc[i][2] += av[t] * w[t].z; acc[i][3] += av[t] * w[t].w;
            }
        }
    }
#pragma unroll
    for (int i = 0; i < 4; ++i) {
        int node = base + n0 + i;
        if (node < N_NODES) {
            *(float4*)&io[(size_t)node * D + d0] =
                make_float4(acc[i][0], acc[i][1], acc[i][2], acc[i][3]);
        }
    }
}

extern "C" void kernel_launch(void* const* d_in, const int* in_sizes, int n_in,
                              void* d_out, int out_size, void* d_ws, size_t ws_size,
                              hipStream_t stream) {
    const float* x = (const float*)d_in[0];
    const int* ei = (const int*)d_in[1];
    const float* wn = (const float*)d_in[2];
    const float* wsf = (const float*)d_in[3];
    const float* bias = (const float*)d_in[4];
    float* out = (float*)d_out;

    // ws layout (u32), ~20 MB:
    // scratch[200000] (fallback offs/deg) bcnt[pad16] y16[3.2M] binned[NB*1024]
    u32* scratch = (u32*)d_ws;
    u32* bcnt = scratch + 2 * N_NODES;
    u32* y16 = bcnt + ((NB + 15) & ~15);
    const size_t Y16W = (size_t)N_NODES * (D / 2);
    u32* binned = y16 + Y16W;
    size_t fixed = 2 * (size_t)N_NODES + ((NB + 15) & ~15);
    size_t need = fixed + Y16W + (size_t)NB * 1024;

    if (ws_size / 4 >= need) {
        const int cap = 1024;
        hipMemsetAsync(bcnt, 0, ((NB + 15) & ~15) * sizeof(u32), stream);
        k_binmm<<<BIN_BLOCKS2 + MM_BLOCKS, 256, 0, stream>>>(
            ei, bcnt, binned, cap, x, wn, wsf, bias, y16, out);
        k_sortgather<<<NB, 256, 0, stream>>>(y16, binned, bcnt, cap, out);
    } else {
        // Fallback: fp32 path.
        u32* offs = scratch;
        u32* deg = offs + N_NODES;
        u32* binned_fb = y16;   // y16 unused in fallback; reuse region
        size_t avail = ws_size / 4 - fixed;
        size_t capz = (avail / NB) & ~(size_t)3;
        int cap = (int)(capz < 1024 ? capz : 1024);
        hipMemsetAsync(bcnt, 0, ((NB + 15) & ~15) * sizeof(u32), stream);
        k_bin2<<<BIN_BLOCKS, 256, 0, stream>>>(ei, bcnt, binned_fb, cap);
        k_sort_fb<<<NB, 256, 0, stream>>>(binned_fb, bcnt, cap, offs, deg);
        k_gather32<<<(N_NODES * 64) / 256, 256, 0, stream>>>(x, binned_fb, offs, deg, out);
        k_gemm_fb<<<(N_NODES + 63) / 64, 256, 0, stream>>>(x, wn, wsf, bias, out);
    }
}

// Round 17
// 90.810 us; speedup vs baseline: 1.1406x; 1.1406x over previous
//
#include <hip/hip_runtime.h>

#define N_NODES 100000
#define N_EDGES 1250000
#define D 64
#define BSH 6                  // 64 nodes per bucket
#define BNODES 64
#define NB 1563                // ceil(100000/64)
#define WSW 68                 // LDS row stride (floats) for fallback GEMM
#define G 512                  // binning blocks / scanB width
#define CHUNK 2444             // per-block edge chunk, 4-aligned
#define MM_BLOCKS ((N_NODES + 127) / 128)     // 782
#define BIN_BLOCKS 128
#define BIN_CHUNK ((N_EDGES + BIN_BLOCKS - 1) / BIN_BLOCKS)

typedef unsigned int u32;
typedef short bf16x8 __attribute__((ext_vector_type(8)));   // 8 bf16 = 4 VGPRs
typedef float f32x4 __attribute__((ext_vector_type(4)));

__device__ __forceinline__ u32 pack_bf16(float lo, float hi) {
    u32 a = __float_as_uint(lo);
    u32 b = __float_as_uint(hi);
    a = (a + 0x7fffu + ((a >> 16) & 1u)) >> 16;   // RNE
    b = (b + 0x7fffu + ((b >> 16) & 1u)) >> 16;
    return a | (b << 16);
}

// ---------------------------------------------------------------------------
// Binning pass A: per-block LDS histogram of a 2444-edge chunk ->
// ghist[b][g] (coalesced layout for pass B). No global atomics.
// ---------------------------------------------------------------------------
__global__ void __launch_bounds__(256) k_hist(const int* __restrict__ ei,
                                              u32* __restrict__ ghist) {
    __shared__ u32 hist[NB];
    int tid = threadIdx.x;
    int g = blockIdx.x;
    int e0 = g * CHUNK, e1 = min(e0 + CHUNK, N_EDGES);
    for (int i = tid; i < NB; i += 256) hist[i] = 0;
    __syncthreads();
    const int4* dp = (const int4*)(ei + N_EDGES + e0);
    int nv = (e1 - e0) >> 2;
    for (int i = tid; i < nv; i += 256) {
        int4 d4 = dp[i];
        atomicAdd(&hist[d4.x >> BSH], 1u);
        atomicAdd(&hist[d4.y >> BSH], 1u);
        atomicAdd(&hist[d4.z >> BSH], 1u);
        atomicAdd(&hist[d4.w >> BSH], 1u);
    }
    __syncthreads();
    for (int i = tid; i < NB; i += 256)
        ghist[(size_t)i * G + g] = hist[i];
}

// ---------------------------------------------------------------------------
// Pass B: per-bucket exclusive scan over G block counts via wave shfl-scan.
// ---------------------------------------------------------------------------
__global__ void __launch_bounds__(512) k_scanB(const u32* __restrict__ ghist,
                                               u32* __restrict__ gbase,
                                               u32* __restrict__ bcnt) {
    __shared__ u32 wt[8];
    int t = threadIdx.x;
    int b = blockIdx.x;
    int lane = t & 63, wv = t >> 6;
    u32 v = ghist[(size_t)b * G + t];
    u32 s = v;
#pragma unroll
    for (int off = 1; off < 64; off <<= 1) {
        u32 n = __shfl_up(s, off, 64);
        if (lane >= off) s += n;
    }
    if (lane == 63) wt[wv] = s;
    __syncthreads();
    u32 add = 0;
#pragma unroll
    for (int q = 0; q < 8; ++q) add += (q < wv) ? wt[q] : 0u;
    u32 incl = s + add;
    gbase[(size_t)b * G + t] = incl - v;
    if (t == G - 1) bcnt[b] = incl;
}

// ---------------------------------------------------------------------------
// Fused scat || mm (independent outputs; one launch -> HW co-schedules).
// Blocks 0..G-1: scatter edges into reserved per-(block,bucket) ranges.
// Blocks G..: MFMA GEMM [Y|Z] = bf16(x) @ [Wn^T|Ws^T]; B-fragments built
// directly from L2-hot wn/wsf (2 float4 + pack per frag).
// ---------------------------------------------------------------------------
__global__ void __launch_bounds__(256) k_scatmm(const int* __restrict__ ei,
                                                const u32* __restrict__ gbase,
                                                u32* __restrict__ binned,
                                                int cap,
                                                const float* __restrict__ x,
                                                const float* __restrict__ wn,
                                                const float* __restrict__ wsf,
                                                const float* __restrict__ bias,
                                                u32* __restrict__ y16,
                                                float* __restrict__ zout) {
    __shared__ u32 cur[NB];
    int tid = threadIdx.x;
    if (blockIdx.x < G) {
        int g = blockIdx.x;
        int e0 = g * CHUNK, e1 = min(e0 + CHUNK, N_EDGES);
        for (int i = tid; i < NB; i += 256)
            cur[i] = gbase[(size_t)i * G + g];
        __syncthreads();
        const int4* sp = (const int4*)(ei + e0);
        const int4* dp = (const int4*)(ei + N_EDGES + e0);
        int nv = (e1 - e0) >> 2;
        for (int i = tid; i < nv; i += 256) {
            int4 s4 = sp[i];
            int4 d4 = dp[i];
            int ss[4] = {s4.x, s4.y, s4.z, s4.w};
            int dd[4] = {d4.x, d4.y, d4.z, d4.w};
#pragma unroll
            for (int u = 0; u < 4; ++u) {
                int b = dd[u] >> BSH;
                u32 loc = atomicAdd(&cur[b], 1u);
                if (loc < (u32)cap)
                    binned[(size_t)b * cap + loc] = ((u32)ss[u] << BSH) | (u32)(dd[u] & (BNODES - 1));
            }
        }
        return;
    }

    // ---- MFMA GEMM part ----
    int w = tid >> 6, l = tid & 63;
    int lg = l >> 4, c = l & 15;
    int nodebase = (blockIdx.x - G) * 128 + w * 32;

    union FU { uint4 u; bf16x8 v; };

    bf16x8 af[2][2];
#pragma unroll
    for (int m = 0; m < 2; ++m) {
        int node = nodebase + m * 16 + c;
        if (node >= N_NODES) node = N_NODES - 1;
        const float4* xr = (const float4*)(x + (size_t)node * D);
#pragma unroll
        for (int h = 0; h < 2; ++h) {
            float4 p0 = xr[h * 8 + lg * 2];
            float4 p1 = xr[h * 8 + lg * 2 + 1];
            FU au;
            au.u.x = pack_bf16(p0.x, p0.y);
            au.u.y = pack_bf16(p0.z, p0.w);
            au.u.z = pack_bf16(p1.x, p1.y);
            au.u.w = pack_bf16(p1.z, p1.w);
            af[m][h] = au.v;
        }
    }

    f32x4 acc[2][8];
#pragma unroll
    for (int m = 0; m < 2; ++m) {
#pragma unroll
        for (int t = 0; t < 4; ++t) acc[m][t] = (f32x4){0.f, 0.f, 0.f, 0.f};
#pragma unroll
        for (int t = 4; t < 8; ++t) {
            float bb = bias[(t - 4) * 16 + c];
            acc[m][t] = (f32x4){bb, bb, bb, bb};
        }
    }

    // B fragments direct from weights: tile t -> row n = t*16 + c of
    // [Wn^T|Ws^T]; half h -> 8 consecutive floats at k0 = h*32 + lg*8.
#pragma unroll
    for (int tc = 0; tc < 2; ++tc) {
        bf16x8 bf[4][2];
#pragma unroll
        for (int tt = 0; tt < 4; ++tt) {
            int n = (tc * 4 + tt) * 16 + c;
            const float* wrow = (n < 64) ? &wn[(size_t)n * 64]
                                         : &wsf[(size_t)(n - 64) * 64];
#pragma unroll
            for (int h = 0; h < 2; ++h) {
                int k0 = h * 32 + lg * 8;
                float4 q0 = *(const float4*)&wrow[k0];
                float4 q1 = *(const float4*)&wrow[k0 + 4];
                FU bu;
                bu.u.x = pack_bf16(q0.x, q0.y);
                bu.u.y = pack_bf16(q0.z, q0.w);
                bu.u.z = pack_bf16(q1.x, q1.y);
                bu.u.w = pack_bf16(q1.z, q1.w);
                bf[tt][h] = bu.v;
            }
        }
#pragma unroll
        for (int m = 0; m < 2; ++m)
#pragma unroll
            for (int tt = 0; tt < 4; ++tt) {
                int t = tc * 4 + tt;
                acc[m][t] = __builtin_amdgcn_mfma_f32_16x16x32_bf16(
                    af[m][0], bf[tt][0], acc[m][t], 0, 0, 0);
                acc[m][t] = __builtin_amdgcn_mfma_f32_16x16x32_bf16(
                    af[m][1], bf[tt][1], acc[m][t], 0, 0, 0);
            }
    }

#pragma unroll
    for (int m = 0; m < 2; ++m) {
        int rowbase = nodebase + m * 16 + lg * 4;
#pragma unroll
        for (int r = 0; r < 4; ++r) {
            int node = rowbase + r;
            bool ok = node < N_NODES;
#pragma unroll
            for (int t = 4; t < 8; ++t) {
                if (ok) zout[(size_t)node * D + (t - 4) * 16 + c] = acc[m][t][r];
            }
#pragma unroll
            for (int t = 0; t < 4; ++t) {
                float v = acc[m][t][r];
                float o = __shfl_xor(v, 1);
                if (ok && !(c & 1))
                    y16[(size_t)node * 32 + t * 8 + (c >> 1)] = pack_bf16(v, o);
            }
        }
    }
}

// ---------------------------------------------------------------------------
// Fused sort + gather: one block = one bucket. Counting-sort the bucket's
// packed edges in LDS (u32 atomics only), then 4 waves gather 16 nodes each:
// 8 predicated uint2 Y-loads in flight, register accumulation,
// out[n] = Z[n] + mean.
// ---------------------------------------------------------------------------
__global__ void __launch_bounds__(256) k_sortgather(const u32* __restrict__ y16,
                                                    const u32* __restrict__ binned,
                                                    const u32* __restrict__ bcnt,
                                                    int cap,
                                                    float* __restrict__ io) {
    __shared__ u32 eh[1024];
    __shared__ u32 srt[1024];
    __shared__ u32 hist[BNODES];
    __shared__ u32 nbase[BNODES];
    __shared__ u32 cur[BNODES];
    int tid = threadIdx.x;
    int b = blockIdx.x;
    int cnt = min((int)bcnt[b], cap);
    const u32* seg = binned + (size_t)b * cap;

    if (tid < BNODES) hist[tid] = 0;
    __syncthreads();
    const uint4* segv = (const uint4*)seg;
    int nv = cnt >> 2;
    for (int i = tid; i < nv; i += 256) {
        uint4 w4 = segv[i];
        *(uint4*)&eh[4 * i] = w4;
        atomicAdd(&hist[w4.x & (BNODES - 1)], 1u);
        atomicAdd(&hist[w4.y & (BNODES - 1)], 1u);
        atomicAdd(&hist[w4.z & (BNODES - 1)], 1u);
        atomicAdd(&hist[w4.w & (BNODES - 1)], 1u);
    }
    for (int i = (cnt & ~3) + tid; i < cnt; i += 256) {
        u32 w = seg[i];
        eh[i] = w;
        atomicAdd(&hist[w & (BNODES - 1)], 1u);
    }
    __syncthreads();
    if (tid < BNODES) {
        u32 v = hist[tid];
        u32 s = v;
#pragma unroll
        for (int off = 1; off < 64; off <<= 1) {
            u32 n = __shfl_up(s, off, 64);
            if (tid >= off) s += n;
        }
        u32 excl = s - v;
        nbase[tid] = excl;
        cur[tid] = excl;
    }
    __syncthreads();
    for (int i = tid; i < cnt; i += 256) {
        u32 w = eh[i];
        u32 p = atomicAdd(&cur[w & (BNODES - 1)], 1u);
        srt[p] = w >> BSH;
    }
    __syncthreads();

    int wv = tid >> 6, lane = tid & 63;
    int sub = lane >> 4;
    int pr = lane & 15;
    const uint2* yv = (const uint2*)y16;
    int nodebase = b << BSH;

    for (int i = 0; i < 16; ++i) {
        int dl = wv * 16 + i;
        int node = nodebase + dl;
        u32 o0 = nbase[dl];
        u32 dg = hist[dl];
        float a0 = 0.f, a1 = 0.f, a2 = 0.f, a3 = 0.f;
        for (u32 r = 0; r < dg; r += 32) {
            uint2 w[8];
#pragma unroll
            for (int t = 0; t < 8; ++t) {
                u32 e = r + 4 * t + sub;
                w[t] = make_uint2(0u, 0u);
                if (e < dg) w[t] = yv[(size_t)srt[o0 + e] * 16 + pr];  // predicated
            }
#pragma unroll
            for (int t = 0; t < 8; ++t) {
                if (r + 4u * (u32)t < dg) {                            // wave-uniform skip
                    a0 += __uint_as_float(w[t].x << 16);
                    a1 += __uint_as_float(w[t].x & 0xffff0000u);
                    a2 += __uint_as_float(w[t].y << 16);
                    a3 += __uint_as_float(w[t].y & 0xffff0000u);
                }
            }
        }
        a0 += __shfl_xor(a0, 16); a1 += __shfl_xor(a1, 16);
        a2 += __shfl_xor(a2, 16); a3 += __shfl_xor(a3, 16);
        a0 += __shfl_xor(a0, 32); a1 += __shfl_xor(a1, 32);
        a2 += __shfl_xor(a2, 32); a3 += __shfl_xor(a3, 32);
        if (sub == 0 && node < N_NODES) {
            float inv = 1.0f / (float)max(dg, 1u);
            float4 z = *(const float4*)&io[(size_t)node * D + 4 * pr];
            *(float4*)&io[(size_t)node * D + 4 * pr] =
                make_float4(z.x + a0 * inv, z.y + a1 * inv, z.z + a2 * inv, z.w + a3 * inv);
        }
    }
}

// ======================= fallback path (small workspace) ====================
__global__ void __launch_bounds__(256) k_bin2(const int* __restrict__ ei,
                                              u32* __restrict__ bcnt,
                                              u32* __restrict__ binned,
                                              int cap) {
    __shared__ u32 hist[NB];
    __shared__ u32 rbase[NB];
    int tid = threadIdx.x;
    int e0 = blockIdx.x * BIN_CHUNK;
    int e1 = min(e0 + BIN_CHUNK, N_EDGES);
    const int* dstp = ei + N_EDGES;
    for (int i = tid; i < NB; i += 256) hist[i] = 0;
    __syncthreads();
    for (int e = e0 + tid; e < e1; e += 256)
        atomicAdd(&hist[dstp[e] >> BSH], 1u);
    __syncthreads();
    for (int i = tid; i < NB; i += 256) {
        u32 h = hist[i];
        rbase[i] = h ? atomicAdd(&bcnt[i], h) : 0u;
        hist[i] = 0;
    }
    __syncthreads();
    for (int e = e0 + tid; e < e1; e += 256) {
        int d = dstp[e];
        int s = ei[e];
        int b = d >> BSH;
        u32 loc = atomicAdd(&hist[b], 1u);
        u32 slot = rbase[b] + loc;
        if (slot < (u32)cap)
            binned[(size_t)b * cap + slot] = ((u32)s << BSH) | (u32)(d & (BNODES - 1));
    }
}

__global__ void __launch_bounds__(256) k_sort_fb(u32* __restrict__ binned,
                                                 const u32* __restrict__ bcnt,
                                                 int cap,
                                                 u32* __restrict__ offs,
                                                 u32* __restrict__ deg) {
    __shared__ u32 eh[1024];
    __shared__ u32 hist[BNODES];
    __shared__ u32 cur[BNODES];
    int tid = threadIdx.x;
    int b = blockIdx.x;
    int cnt = min((int)bcnt[b], cap);
    u32* seg = binned + (size_t)b * cap;
    if (tid < BNODES) hist[tid] = 0;
    __syncthreads();
    for (int i = tid; i < cnt; i += 256) {
        u32 w = seg[i];
        eh[i] = w;
        atomicAdd(&hist[w & (BNODES - 1)], 1u);
    }
    __syncthreads();
    if (tid < BNODES) {
        u32 v = hist[tid];
        u32 s = v;
#pragma unroll
        for (int off = 1; off < 64; off <<= 1) {
            u32 n = __shfl_up(s, off, 64);
            if (tid >= off) s += n;
        }
        u32 excl = s - v;
        cur[tid] = excl;
        int node = (b << BSH) + tid;
        if (node < N_NODES) {
            offs[node] = (u32)((size_t)b * cap + excl);
            deg[node] = v;
        }
    }
    __syncthreads();
    for (int i = tid; i < cnt; i += 256) {
        u32 w = eh[i];
        u32 p = atomicAdd(&cur[w & (BNODES - 1)], 1u);
        seg[p] = w >> BSH;
    }
}

__global__ void __launch_bounds__(256) k_gather32(const float* __restrict__ x,
                                                  const u32* __restrict__ binned,
                                                  const u32* __restrict__ offs,
                                                  const u32* __restrict__ deg,
                                                  float* __restrict__ agg) {
    int tid = blockIdx.x * 256 + threadIdx.x;
    int node = tid >> 6;
    int d = tid & 63;
    if (node >= N_NODES) return;
    u32 o0 = offs[node], dg = deg[node];
    u32 o1 = o0 + dg;
    float s = 0.f;
    u32 j = o0;
    for (; j + 8 <= o1; j += 8) {
        u32 e[8];
        float v[8];
#pragma unroll
        for (int t = 0; t < 8; ++t) e[t] = binned[j + t];
#pragma unroll
        for (int t = 0; t < 8; ++t) v[t] = x[(size_t)e[t] * D + d];
#pragma unroll
        for (int t = 0; t < 8; ++t) s += v[t];
    }
    for (; j < o1; ++j) s += x[(size_t)binned[j] * D + d];
    agg[(size_t)node * D + d] = s / (float)max(dg, 1u);
}

__global__ void __launch_bounds__(256) k_gemm_fb(const float* __restrict__ x,
                                                 const float* __restrict__ wn,
                                                 const float* __restrict__ wsf,
                                                 const float* __restrict__ bias,
                                                 float* __restrict__ io) {
    __shared__ float At[BNODES * WSW];
    __shared__ float Wt[128 * WSW];
    int tid = threadIdx.x;
    int base = blockIdx.x * 64;
    const float4* iop = (const float4*)io;
    const float4* xp  = (const float4*)x;
    for (int i = tid; i < 4096; i += 256) {
        int d = i >> 6, k = i & 63;
        Wt[k * WSW + d] = wn[i];
        Wt[(64 + k) * WSW + d] = wsf[i];
    }
    for (int i = tid; i < 1024; i += 256) {
        int r = i >> 4, q = i & 15;
        int node = base + r;
        float4 v = make_float4(0.f, 0.f, 0.f, 0.f);
        if (node < N_NODES) v = iop[(size_t)node * 16 + q];
        *(float4*)&At[r * WSW + q * 4] = v;
    }
    __syncthreads();
    int tn = tid >> 4, td = tid & 15;
    int n0 = tn * 4, d0 = td * 4;
    float4 b4 = *(const float4*)&bias[d0];
    float acc[4][4];
#pragma unroll
    for (int i = 0; i < 4; ++i) {
        acc[i][0] = b4.x; acc[i][1] = b4.y; acc[i][2] = b4.z; acc[i][3] = b4.w;
    }
#pragma unroll 8
    for (int kc = 0; kc < 16; ++kc) {
        float4 a[4], w[4];
#pragma unroll
        for (int i = 0; i < 4; ++i) a[i] = *(const float4*)&At[(n0 + i) * WSW + kc * 4];
#pragma unroll
        for (int t = 0; t < 4; ++t) w[t] = *(const float4*)&Wt[(kc * 4 + t) * WSW + d0];
#pragma unroll
        for (int i = 0; i < 4; ++i) {
            const float av[4] = {a[i].x, a[i].y, a[i].z, a[i].w};
#pragma unroll
            for (int t = 0; t < 4; ++t) {
                acc[i][0] += av[t] * w[t].x; acc[i][1] += av[t] * w[t].y;
                acc[i][2] += av[t] * w[t].z; acc[i][3] += av[t] * w[t].w;
            }
        }
    }
    __syncthreads();
    for (int i = tid; i < 1024; i += 256) {
        int r = i >> 4, q = i & 15;
        int node = base + r;
        float4 v = make_float4(0.f, 0.f, 0.f, 0.f);
        if (node < N_NODES) v = xp[(size_t)node * 16 + q];
        *(float4*)&At[r * WSW + q * 4] = v;
    }
    __syncthreads();
#pragma unroll 8
    for (int kc = 0; kc < 16; ++kc) {
        float4 a[4], w[4];
#pragma unroll
        for (int i = 0; i < 4; ++i) a[i] = *(const float4*)&At[(n0 + i) * WSW + kc * 4];
#pragma unroll
        for (int t = 0; t < 4; ++t) w[t] = *(const float4*)&Wt[(64 + kc * 4 + t) * WSW + d0];
#pragma unroll
        for (int i = 0; i < 4; ++i) {
            const float av[4] = {a[i].x, a[i].y, a[i].z, a[i].w};
#pragma unroll
            for (int t = 0; t < 4; ++t) {
                acc[i][0] += av[t] * w[t].x; acc[i][1] += av[t] * w[t].y;
                acc[i][2] += av[t] * w[t].z; acc[i][3] += av[t] * w[t].w;
            }
        }
    }
#pragma unroll
    for (int i = 0; i < 4; ++i) {
        int node = base + n0 + i;
        if (node < N_NODES) {
            *(float4*)&io[(size_t)node * D + d0] =
                make_float4(acc[i][0], acc[i][1], acc[i][2], acc[i][3]);
        }
    }
}

extern "C" void kernel_launch(void* const* d_in, const int* in_sizes, int n_in,
                              void* d_out, int out_size, void* d_ws, size_t ws_size,
                              hipStream_t stream) {
    const float* x = (const float*)d_in[0];
    const int* ei = (const int*)d_in[1];
    const float* wn = (const float*)d_in[2];
    const float* wsf = (const float*)d_in[3];
    const float* bias = (const float*)d_in[4];
    float* out = (float*)d_out;

    // ws layout (u32), no aliasing (~27 MB):
    // scratch[200000] (fallback offs/deg) bcnt[pad16] y16[3.2M] binned[NB*1024]
    // ghist[NB*G] gbase[NB*G]
    u32* scratch = (u32*)d_ws;
    u32* bcnt = scratch + 2 * N_NODES;
    u32* y16 = bcnt + ((NB + 15) & ~15);
    const size_t Y16W = (size_t)N_NODES * (D / 2);
    u32* binned = y16 + Y16W;
    u32* ghist = binned + (size_t)NB * 1024;
    u32* gbase = ghist + (size_t)NB * G;
    size_t fixed = 2 * (size_t)N_NODES + ((NB + 15) & ~15);
    size_t need = fixed + Y16W + (size_t)NB * 1024 + 2 * (size_t)NB * G;

    if (ws_size / 4 >= need) {
        const int cap = 1024;
        k_hist<<<G, 256, 0, stream>>>(ei, ghist);
        k_scanB<<<NB, 512, 0, stream>>>(ghist, gbase, bcnt);
        k_scatmm<<<G + MM_BLOCKS, 256, 0, stream>>>(ei, gbase, binned, cap,
                                                    x, wn, wsf, bias, y16, out);
        k_sortgather<<<NB, 256, 0, stream>>>(y16, binned, bcnt, cap, out);
    } else {
        // Fallback: fp32 path.
        u32* offs = scratch;
        u32* deg = offs + N_NODES;
        u32* binned_fb = y16;   // y16 unused in fallback; reuse region
        size_t avail = ws_size / 4 - fixed;
        size_t capz = (avail / NB) & ~(size_t)3;
        int cap = (int)(capz < 1024 ? capz : 1024);
        hipMemsetAsync(bcnt, 0, ((NB + 15) & ~15) * sizeof(u32), stream);
        k_bin2<<<BIN_BLOCKS, 256, 0, stream>>>(ei, bcnt, binned_fb, cap);
        k_sort_fb<<<NB, 256, 0, stream>>>(binned_fb, bcnt, cap, offs, deg);
        k_gather32<<<(N_NODES * 64) / 256, 256, 0, stream>>>(x, binned_fb, offs, deg, out);
        k_gemm_fb<<<(N_NODES + 63) / 64, 256, 0, stream>>>(x, wn, wsf, bias, out);
    }
}

// Round 18
// 83.616 us; speedup vs baseline: 1.2387x; 1.0860x over previous
//
#include <hip/hip_runtime.h>

#define N_NODES 100000
#define N_EDGES 1250000
#define D 64
#define BSH 6                  // 64 nodes per bucket
#define BNODES 64
#define NB 1563                // ceil(100000/64)
#define WSW 68                 // LDS row stride (floats) for fallback GEMM
#define G 512                  // binning blocks / scanB width
#define CHUNK 2444             // per-block edge chunk, 4-aligned
#define MM_BLOCKS ((N_NODES + 127) / 128)     // 782
#define BIN_BLOCKS 128
#define BIN_CHUNK ((N_EDGES + BIN_BLOCKS - 1) / BIN_BLOCKS)

typedef unsigned int u32;
typedef short bf16x8 __attribute__((ext_vector_type(8)));   // 8 bf16 = 4 VGPRs
typedef float f32x4 __attribute__((ext_vector_type(4)));

__device__ __forceinline__ u32 pack_bf16(float lo, float hi) {
    u32 a = __float_as_uint(lo);
    u32 b = __float_as_uint(hi);
    a = (a + 0x7fffu + ((a >> 16) & 1u)) >> 16;   // RNE
    b = (b + 0x7fffu + ((b >> 16) & 1u)) >> 16;
    return a | (b << 16);
}

// ---------------------------------------------------------------------------
// Fused: blocks 0..G-1 do binning pass A (per-block LDS histogram ->
// ghist[b][g]); block G packs B = [Wn^T|Ws^T] into MFMA B-fragment layout.
// ---------------------------------------------------------------------------
__global__ void __launch_bounds__(256) k_histw(const int* __restrict__ ei,
                                               u32* __restrict__ ghist,
                                               const float* __restrict__ wn,
                                               const float* __restrict__ wsf,
                                               u32* __restrict__ bfrag) {
    __shared__ u32 hist[NB];
    int tid = threadIdx.x;
    if (blockIdx.x < G) {
        int g = blockIdx.x;
        int e0 = g * CHUNK, e1 = min(e0 + CHUNK, N_EDGES);
        for (int i = tid; i < NB; i += 256) hist[i] = 0;
        __syncthreads();
        const int4* dp = (const int4*)(ei + N_EDGES + e0);
        int nv = (e1 - e0) >> 2;
        for (int i = tid; i < nv; i += 256) {
            int4 d4 = dp[i];
            atomicAdd(&hist[d4.x >> BSH], 1u);
            atomicAdd(&hist[d4.y >> BSH], 1u);
            atomicAdd(&hist[d4.z >> BSH], 1u);
            atomicAdd(&hist[d4.w >> BSH], 1u);
        }
        __syncthreads();
        for (int i = tid; i < NB; i += 256)
            ghist[(size_t)i * G + g] = hist[i];
    } else {
        for (int i = tid; i < 4096; i += 256) {
            int t = i >> 9, h = (i >> 8) & 1, l = (i >> 2) & 63, q = i & 3;
            int k0 = h * 32 + (l >> 4) * 8 + 2 * q;
            int n = t * 16 + (l & 15);
            const float* w = (n < 64) ? &wn[(size_t)n * 64] : &wsf[(size_t)(n - 64) * 64];
            bfrag[i] = pack_bf16(w[k0], w[k0 + 1]);
        }
    }
}

// ---------------------------------------------------------------------------
// Pass B: per-bucket exclusive scan over G block counts via wave shfl-scan.
// ---------------------------------------------------------------------------
__global__ void __launch_bounds__(512) k_scanB(const u32* __restrict__ ghist,
                                               u32* __restrict__ gbase,
                                               u32* __restrict__ bcnt) {
    __shared__ u32 wt[8];
    int t = threadIdx.x;
    int b = blockIdx.x;
    int lane = t & 63, wv = t >> 6;
    u32 v = ghist[(size_t)b * G + t];
    u32 s = v;
#pragma unroll
    for (int off = 1; off < 64; off <<= 1) {
        u32 n = __shfl_up(s, off, 64);
        if (lane >= off) s += n;
    }
    if (lane == 63) wt[wv] = s;
    __syncthreads();
    u32 add = 0;
#pragma unroll
    for (int q = 0; q < 8; ++q) add += (q < wv) ? wt[q] : 0u;
    u32 incl = s + add;
    gbase[(size_t)b * G + t] = incl - v;
    if (t == G - 1) bcnt[b] = incl;
}

// ---------------------------------------------------------------------------
// Fused scat || mm (independent outputs; one launch -> HW co-schedules).
// Blocks 0..G-1: scatter edges into reserved per-(block,bucket) ranges.
// Blocks G..: MFMA GEMM [Y|Z] = bf16(x) @ B; Y bf16 -> y16, Z+bias -> d_out.
// B fragments from the prepacked L2-hot bfrag buffer (coalesced loads).
// ---------------------------------------------------------------------------
__global__ void __launch_bounds__(256) k_scatmm(const int* __restrict__ ei,
                                                const u32* __restrict__ gbase,
                                                u32* __restrict__ binned,
                                                int cap,
                                                const float* __restrict__ x,
                                                const u32* __restrict__ bfrag,
                                                const float* __restrict__ bias,
                                                u32* __restrict__ y16,
                                                float* __restrict__ zout) {
    __shared__ u32 cur[NB];
    int tid = threadIdx.x;
    if (blockIdx.x < G) {
        int g = blockIdx.x;
        int e0 = g * CHUNK, e1 = min(e0 + CHUNK, N_EDGES);
        for (int i = tid; i < NB; i += 256)
            cur[i] = gbase[(size_t)i * G + g];
        __syncthreads();
        const int4* sp = (const int4*)(ei + e0);
        const int4* dp = (const int4*)(ei + N_EDGES + e0);
        int nv = (e1 - e0) >> 2;
        for (int i = tid; i < nv; i += 256) {
            int4 s4 = sp[i];
            int4 d4 = dp[i];
            int ss[4] = {s4.x, s4.y, s4.z, s4.w};
            int dd[4] = {d4.x, d4.y, d4.z, d4.w};
#pragma unroll
            for (int u = 0; u < 4; ++u) {
                int b = dd[u] >> BSH;
                u32 loc = atomicAdd(&cur[b], 1u);
                if (loc < (u32)cap)
                    binned[(size_t)b * cap + loc] = ((u32)ss[u] << BSH) | (u32)(dd[u] & (BNODES - 1));
            }
        }
        return;
    }

    // ---- MFMA GEMM part ----
    int w = tid >> 6, l = tid & 63;
    int lg = l >> 4, c = l & 15;
    int nodebase = (blockIdx.x - G) * 128 + w * 32;

    union FU { uint4 u; bf16x8 v; };

    bf16x8 af[2][2];
#pragma unroll
    for (int m = 0; m < 2; ++m) {
        int node = nodebase + m * 16 + c;
        if (node >= N_NODES) node = N_NODES - 1;
        const float4* xr = (const float4*)(x + (size_t)node * D);
#pragma unroll
        for (int h = 0; h < 2; ++h) {
            float4 p0 = xr[h * 8 + lg * 2];
            float4 p1 = xr[h * 8 + lg * 2 + 1];
            FU au;
            au.u.x = pack_bf16(p0.x, p0.y);
            au.u.y = pack_bf16(p0.z, p0.w);
            au.u.z = pack_bf16(p1.x, p1.y);
            au.u.w = pack_bf16(p1.z, p1.w);
            af[m][h] = au.v;
        }
    }

    f32x4 acc[2][8];
#pragma unroll
    for (int m = 0; m < 2; ++m) {
#pragma unroll
        for (int t = 0; t < 4; ++t) acc[m][t] = (f32x4){0.f, 0.f, 0.f, 0.f};
#pragma unroll
        for (int t = 4; t < 8; ++t) {
            float bb = bias[(t - 4) * 16 + c];
            acc[m][t] = (f32x4){bb, bb, bb, bb};
        }
    }

    const uint4* bp = (const uint4*)bfrag;
#pragma unroll
    for (int tc = 0; tc < 2; ++tc) {
        bf16x8 bf[4][2];
#pragma unroll
        for (int tt = 0; tt < 4; ++tt)
#pragma unroll
            for (int h = 0; h < 2; ++h) {
                FU bu;
                bu.u = bp[(((tc * 4 + tt) * 2 + h) * 64) + l];
                bf[tt][h] = bu.v;
            }
#pragma unroll
        for (int m = 0; m < 2; ++m)
#pragma unroll
            for (int tt = 0; tt < 4; ++tt) {
                int t = tc * 4 + tt;
                acc[m][t] = __builtin_amdgcn_mfma_f32_16x16x32_bf16(
                    af[m][0], bf[tt][0], acc[m][t], 0, 0, 0);
                acc[m][t] = __builtin_amdgcn_mfma_f32_16x16x32_bf16(
                    af[m][1], bf[tt][1], acc[m][t], 0, 0, 0);
            }
    }

#pragma unroll
    for (int m = 0; m < 2; ++m) {
        int rowbase = nodebase + m * 16 + lg * 4;
#pragma unroll
        for (int r = 0; r < 4; ++r) {
            int node = rowbase + r;
            bool ok = node < N_NODES;
#pragma unroll
            for (int t = 4; t < 8; ++t) {
                if (ok) zout[(size_t)node * D + (t - 4) * 16 + c] = acc[m][t][r];
            }
#pragma unroll
            for (int t = 0; t < 4; ++t) {
                float v = acc[m][t][r];
                float o = __shfl_xor(v, 1);
                if (ok && !(c & 1))
                    y16[(size_t)node * 32 + t * 8 + (c >> 1)] = pack_bf16(v, o);
            }
        }
    }
}

// ---------------------------------------------------------------------------
// Fused sort + gather: one block = one bucket. Counting-sort the bucket's
// packed edges in LDS (u32 atomics only), then 4 waves gather 16 nodes each:
// 8 predicated uint2 Y-loads in flight, register accumulation,
// out[n] = Z[n] + mean.
// ---------------------------------------------------------------------------
__global__ void __launch_bounds__(256) k_sortgather(const u32* __restrict__ y16,
                                                    const u32* __restrict__ binned,
                                                    const u32* __restrict__ bcnt,
                                                    int cap,
                                                    float* __restrict__ io) {
    __shared__ u32 eh[1024];
    __shared__ u32 srt[1024];
    __shared__ u32 hist[BNODES];
    __shared__ u32 nbase[BNODES];
    __shared__ u32 cur[BNODES];
    int tid = threadIdx.x;
    int b = blockIdx.x;
    int cnt = min((int)bcnt[b], cap);
    const u32* seg = binned + (size_t)b * cap;

    if (tid < BNODES) hist[tid] = 0;
    __syncthreads();
    const uint4* segv = (const uint4*)seg;
    int nv = cnt >> 2;
    for (int i = tid; i < nv; i += 256) {
        uint4 w4 = segv[i];
        *(uint4*)&eh[4 * i] = w4;
        atomicAdd(&hist[w4.x & (BNODES - 1)], 1u);
        atomicAdd(&hist[w4.y & (BNODES - 1)], 1u);
        atomicAdd(&hist[w4.z & (BNODES - 1)], 1u);
        atomicAdd(&hist[w4.w & (BNODES - 1)], 1u);
    }
    for (int i = (cnt & ~3) + tid; i < cnt; i += 256) {
        u32 w = seg[i];
        eh[i] = w;
        atomicAdd(&hist[w & (BNODES - 1)], 1u);
    }
    __syncthreads();
    if (tid < BNODES) {
        u32 v = hist[tid];
        u32 s = v;
#pragma unroll
        for (int off = 1; off < 64; off <<= 1) {
            u32 n = __shfl_up(s, off, 64);
            if (tid >= off) s += n;
        }
        u32 excl = s - v;
        nbase[tid] = excl;
        cur[tid] = excl;
    }
    __syncthreads();
    for (int i = tid; i < cnt; i += 256) {
        u32 w = eh[i];
        u32 p = atomicAdd(&cur[w & (BNODES - 1)], 1u);
        srt[p] = w >> BSH;
    }
    __syncthreads();

    int wv = tid >> 6, lane = tid & 63;
    int sub = lane >> 4;
    int pr = lane & 15;
    const uint2* yv = (const uint2*)y16;
    int nodebase = b << BSH;

    for (int i = 0; i < 16; ++i) {
        int dl = wv * 16 + i;
        int node = nodebase + dl;
        u32 o0 = nbase[dl];
        u32 dg = hist[dl];
        float a0 = 0.f, a1 = 0.f, a2 = 0.f, a3 = 0.f;
        for (u32 r = 0; r < dg; r += 32) {
            uint2 w[8];
#pragma unroll
            for (int t = 0; t < 8; ++t) {
                u32 e = r + 4 * t + sub;
                w[t] = make_uint2(0u, 0u);
                if (e < dg) w[t] = yv[(size_t)srt[o0 + e] * 16 + pr];  // predicated
            }
#pragma unroll
            for (int t = 0; t < 8; ++t) {
                if (r + 4u * (u32)t < dg) {                            // wave-uniform skip
                    a0 += __uint_as_float(w[t].x << 16);
                    a1 += __uint_as_float(w[t].x & 0xffff0000u);
                    a2 += __uint_as_float(w[t].y << 16);
                    a3 += __uint_as_float(w[t].y & 0xffff0000u);
                }
            }
        }
        a0 += __shfl_xor(a0, 16); a1 += __shfl_xor(a1, 16);
        a2 += __shfl_xor(a2, 16); a3 += __shfl_xor(a3, 16);
        a0 += __shfl_xor(a0, 32); a1 += __shfl_xor(a1, 32);
        a2 += __shfl_xor(a2, 32); a3 += __shfl_xor(a3, 32);
        if (sub == 0 && node < N_NODES) {
            float inv = 1.0f / (float)max(dg, 1u);
            float4 z = *(const float4*)&io[(size_t)node * D + 4 * pr];
            *(float4*)&io[(size_t)node * D + 4 * pr] =
                make_float4(z.x + a0 * inv, z.y + a1 * inv, z.z + a2 * inv, z.w + a3 * inv);
        }
    }
}

// ======================= fallback path (small workspace) ====================
__global__ void __launch_bounds__(256) k_bin2(const int* __restrict__ ei,
                                              u32* __restrict__ bcnt,
                                              u32* __restrict__ binned,
                                              int cap) {
    __shared__ u32 hist[NB];
    __shared__ u32 rbase[NB];
    int tid = threadIdx.x;
    int e0 = blockIdx.x * BIN_CHUNK;
    int e1 = min(e0 + BIN_CHUNK, N_EDGES);
    const int* dstp = ei + N_EDGES;
    for (int i = tid; i < NB; i += 256) hist[i] = 0;
    __syncthreads();
    for (int e = e0 + tid; e < e1; e += 256)
        atomicAdd(&hist[dstp[e] >> BSH], 1u);
    __syncthreads();
    for (int i = tid; i < NB; i += 256) {
        u32 h = hist[i];
        rbase[i] = h ? atomicAdd(&bcnt[i], h) : 0u;
        hist[i] = 0;
    }
    __syncthreads();
    for (int e = e0 + tid; e < e1; e += 256) {
        int d = dstp[e];
        int s = ei[e];
        int b = d >> BSH;
        u32 loc = atomicAdd(&hist[b], 1u);
        u32 slot = rbase[b] + loc;
        if (slot < (u32)cap)
            binned[(size_t)b * cap + slot] = ((u32)s << BSH) | (u32)(d & (BNODES - 1));
    }
}

__global__ void __launch_bounds__(256) k_sort_fb(u32* __restrict__ binned,
                                                 const u32* __restrict__ bcnt,
                                                 int cap,
                                                 u32* __restrict__ offs,
                                                 u32* __restrict__ deg) {
    __shared__ u32 eh[1024];
    __shared__ u32 hist[BNODES];
    __shared__ u32 cur[BNODES];
    int tid = threadIdx.x;
    int b = blockIdx.x;
    int cnt = min((int)bcnt[b], cap);
    u32* seg = binned + (size_t)b * cap;
    if (tid < BNODES) hist[tid] = 0;
    __syncthreads();
    for (int i = tid; i < cnt; i += 256) {
        u32 w = seg[i];
        eh[i] = w;
        atomicAdd(&hist[w & (BNODES - 1)], 1u);
    }
    __syncthreads();
    if (tid < BNODES) {
        u32 v = hist[tid];
        u32 s = v;
#pragma unroll
        for (int off = 1; off < 64; off <<= 1) {
            u32 n = __shfl_up(s, off, 64);
            if (tid >= off) s += n;
        }
        u32 excl = s - v;
        cur[tid] = excl;
        int node = (b << BSH) + tid;
        if (node < N_NODES) {
            offs[node] = (u32)((size_t)b * cap + excl);
            deg[node] = v;
        }
    }
    __syncthreads();
    for (int i = tid; i < cnt; i += 256) {
        u32 w = eh[i];
        u32 p = atomicAdd(&cur[w & (BNODES - 1)], 1u);
        seg[p] = w >> BSH;
    }
}

__global__ void __launch_bounds__(256) k_gather32(const float* __restrict__ x,
                                                  const u32* __restrict__ binned,
                                                  const u32* __restrict__ offs,
                                                  const u32* __restrict__ deg,
                                                  float* __restrict__ agg) {
    int tid = blockIdx.x * 256 + threadIdx.x;
    int node = tid >> 6;
    int d = tid & 63;
    if (node >= N_NODES) return;
    u32 o0 = offs[node], dg = deg[node];
    u32 o1 = o0 + dg;
    float s = 0.f;
    u32 j = o0;
    for (; j + 8 <= o1; j += 8) {
        u32 e[8];
        float v[8];
#pragma unroll
        for (int t = 0; t < 8; ++t) e[t] = binned[j + t];
#pragma unroll
        for (int t = 0; t < 8; ++t) v[t] = x[(size_t)e[t] * D + d];
#pragma unroll
        for (int t = 0; t < 8; ++t) s += v[t];
    }
    for (; j < o1; ++j) s += x[(size_t)binned[j] * D + d];
    agg[(size_t)node * D + d] = s / (float)max(dg, 1u);
}

__global__ void __launch_bounds__(256) k_gemm_fb(const float* __restrict__ x,
                                                 const float* __restrict__ wn,
                                                 const float* __restrict__ wsf,
                                                 const float* __restrict__ bias,
                                                 float* __restrict__ io) {
    __shared__ float At[BNODES * WSW];
    __shared__ float Wt[128 * WSW];
    int tid = threadIdx.x;
    int base = blockIdx.x * 64;
    const float4* iop = (const float4*)io;
    const float4* xp  = (const float4*)x;
    for (int i = tid; i < 4096; i += 256) {
        int d = i >> 6, k = i & 63;
        Wt[k * WSW + d] = wn[i];
        Wt[(64 + k) * WSW + d] = wsf[i];
    }
    for (int i = tid; i < 1024; i += 256) {
        int r = i >> 4, q = i & 15;
        int node = base + r;
        float4 v = make_float4(0.f, 0.f, 0.f, 0.f);
        if (node < N_NODES) v = iop[(size_t)node * 16 + q];
        *(float4*)&At[r * WSW + q * 4] = v;
    }
    __syncthreads();
    int tn = tid >> 4, td = tid & 15;
    int n0 = tn * 4, d0 = td * 4;
    float4 b4 = *(const float4*)&bias[d0];
    float acc[4][4];
#pragma unroll
    for (int i = 0; i < 4; ++i) {
        acc[i][0] = b4.x; acc[i][1] = b4.y; acc[i][2] = b4.z; acc[i][3] = b4.w;
    }
#pragma unroll 8
    for (int kc = 0; kc < 16; ++kc) {
        float4 a[4], w[4];
#pragma unroll
        for (int i = 0; i < 4; ++i) a[i] = *(const float4*)&At[(n0 + i) * WSW + kc * 4];
#pragma unroll
        for (int t = 0; t < 4; ++t) w[t] = *(const float4*)&Wt[(kc * 4 + t) * WSW + d0];
#pragma unroll
        for (int i = 0; i < 4; ++i) {
            const float av[4] = {a[i].x, a[i].y, a[i].z, a[i].w};
#pragma unroll
            for (int t = 0; t < 4; ++t) {
                acc[i][0] += av[t] * w[t].x; acc[i][1] += av[t] * w[t].y;
                acc[i][2] += av[t] * w[t].z; acc[i][3] += av[t] * w[t].w;
            }
        }
    }
    __syncthreads();
    for (int i = tid; i < 1024; i += 256) {
        int r = i >> 4, q = i & 15;
        int node = base + r;
        float4 v = make_float4(0.f, 0.f, 0.f, 0.f);
        if (node < N_NODES) v = xp[(size_t)node * 16 + q];
        *(float4*)&At[r * WSW + q * 4] = v;
    }
    __syncthreads();
#pragma unroll 8
    for (int kc = 0; kc < 16; ++kc) {
        float4 a[4], w[4];
#pragma unroll
        for (int i = 0; i < 4; ++i) a[i] = *(const float4*)&At[(n0 + i) * WSW + kc * 4];
#pragma unroll
        for (int t = 0; t < 4; ++t) w[t] = *(const float4*)&Wt[(64 + kc * 4 + t) * WSW + d0];
#pragma unroll
        for (int i = 0; i < 4; ++i) {
            const float av[4] = {a[i].x, a[i].y, a[i].z, a[i].w};
#pragma unroll
            for (int t = 0; t < 4; ++t) {
                acc[i][0] += av[t] * w[t].x; acc[i][1] += av[t] * w[t].y;
                acc[i][2] += av[t] * w[t].z; acc[i][3] += av[t] * w[t].w;
            }
        }
    }
#pragma unroll
    for (int i = 0; i < 4; ++i) {
        int node = base + n0 + i;
        if (node < N_NODES) {
            *(float4*)&io[(size_t)node * D + d0] =
                make_float4(acc[i][0], acc[i][1], acc[i][2], acc[i][3]);
        }
    }
}

extern "C" void kernel_launch(void* const* d_in, const int* in_sizes, int n_in,
                              void* d_out, int out_size, void* d_ws, size_t ws_size,
                              hipStream_t stream) {
    const float* x = (const float*)d_in[0];
    const int* ei = (const int*)d_in[1];
    const float* wn = (const float*)d_in[2];
    const float* wsf = (const float*)d_in[3];
    const float* bias = (const float*)d_in[4];
    float* out = (float*)d_out;

    // ws layout (u32), no aliasing (~27 MB):
    // scratch[200000] (fallback offs/deg) bcnt[pad16] bfrag[8192] y16[3.2M]
    // binned[NB*1024] ghist[NB*G] gbase[NB*G]
    u32* scratch = (u32*)d_ws;
    u32* bcnt = scratch + 2 * N_NODES;
    u32* bfrag = bcnt + ((NB + 15) & ~15);
    u32* y16 = bfrag + 8192;
    const size_t Y16W = (size_t)N_NODES * (D / 2);
    u32* binned = y16 + Y16W;
    u32* ghist = binned + (size_t)NB * 1024;
    u32* gbase = ghist + (size_t)NB * G;
    size_t fixed = 2 * (size_t)N_NODES + ((NB + 15) & ~15) + 8192;
    size_t need = fixed + Y16W + (size_t)NB * 1024 + 2 * (size_t)NB * G;

    if (ws_size / 4 >= need) {
        const int cap = 1024;
        k_histw<<<G + 1, 256, 0, stream>>>(ei, ghist, wn, wsf, bfrag);
        k_scanB<<<NB, 512, 0, stream>>>(ghist, gbase, bcnt);
        k_scatmm<<<G + MM_BLOCKS, 256, 0, stream>>>(ei, gbase, binned, cap,
                                                    x, bfrag, wn == nullptr ? nullptr : bias, y16, out);
        k_sortgather<<<NB, 256, 0, stream>>>(y16, binned, bcnt, cap, out);
    } else {
        // Fallback: fp32 path.
        u32* offs = scratch;
        u32* deg = offs + N_NODES;
        u32* binned_fb = y16;   // y16 unused in fallback; reuse region
        size_t avail = ws_size / 4 - fixed;
        size_t capz = (avail / NB) & ~(size_t)3;
        int cap = (int)(capz < 1024 ? capz : 1024);
        hipMemsetAsync(bcnt, 0, ((NB + 15) & ~15) * sizeof(u32), stream);
        k_bin2<<<BIN_BLOCKS, 256, 0, stream>>>(ei, bcnt, binned_fb, cap);
        k_sort_fb<<<NB, 256, 0, stream>>>(binned_fb, bcnt, cap, offs, deg);
        k_gather32<<<(N_NODES * 64) / 256, 256, 0, stream>>>(x, binned_fb, offs, deg, out);
        k_gemm_fb<<<(N_NODES + 63) / 64, 256, 0, stream>>>(x, wn, wsf, bias, out);
    }
}